// Round 7
// baseline (920.118 us; speedup 1.0000x reference)
//
#include <hip/hip_runtime.h>
#include <hip/hip_bf16.h>
#include <cmath>

typedef __bf16 bf16_t;
typedef __bf16 bf16x8 __attribute__((ext_vector_type(8)));
typedef float f32x4 __attribute__((ext_vector_type(4)));

#define DEV __device__ __forceinline__
#define MEMFENCE asm volatile("" ::: "memory")

static constexpr int BB = 2, SS = 2048, DD = 2048, HH = 16, HDIM = 128, II = 5504;
static constexpr int MM = BB * SS; // 4096

DEV void gload_lds16(const void* g, void* l) {
    __builtin_amdgcn_global_load_lds(
        (__attribute__((address_space(1))) void*)const_cast<void*>(g),
        (__attribute__((address_space(3))) void*)l, 16, 0, 0);
}

// ---------------- RMSNorm: f32 in -> bf16 out ----------------
__global__ __launch_bounds__(256) void rmsnorm_k(const float* __restrict__ x,
                                                 const float* __restrict__ w,
                                                 bf16_t* __restrict__ out) {
    int row = blockIdx.x;
    int t = threadIdx.x;
    const float4* xr = (const float4*)(x + (size_t)row * DD);
    float4 a = xr[t];
    float4 b = xr[t + 256];
    float ss = a.x * a.x + a.y * a.y + a.z * a.z + a.w * a.w +
               b.x * b.x + b.y * b.y + b.z * b.z + b.w * b.w;
    for (int m = 1; m < 64; m <<= 1) ss += __shfl_xor(ss, m);
    __shared__ float red[4];
    int lane = t & 63, wv = t >> 6;
    if (lane == 0) red[wv] = ss;
    __syncthreads();
    float scale = rsqrtf((red[0] + red[1] + red[2] + red[3]) * (1.0f / DD) + 1e-6f);
    const float4* w4 = (const float4*)w;
    float4 wa = w4[t], wb = w4[t + 256];
    bf16_t* o = out + (size_t)row * DD;
    union { bf16_t h[4]; ushort4 u; } pa, pb;
    pa.h[0] = (bf16_t)(a.x * scale * wa.x); pa.h[1] = (bf16_t)(a.y * scale * wa.y);
    pa.h[2] = (bf16_t)(a.z * scale * wa.z); pa.h[3] = (bf16_t)(a.w * scale * wa.w);
    pb.h[0] = (bf16_t)(b.x * scale * wb.x); pb.h[1] = (bf16_t)(b.y * scale * wb.y);
    pb.h[2] = (bf16_t)(b.z * scale * wb.z); pb.h[3] = (bf16_t)(b.w * scale * wb.w);
    ((ushort4*)o)[t] = pa.u;
    ((ushort4*)o)[t + 256] = pb.u;
}

// ---------------- RoPE tables ----------------
__global__ void rope_tables_k(float* __restrict__ cosb, float* __restrict__ sinb) {
    int s = blockIdx.x;
    int d = threadIdx.x;       // 0..127
    int j = d & 63;
    float inv = powf(10000.0f, -(2.0f * (float)j) / 128.0f);
    float ang = (float)s * inv;
    cosb[s * HDIM + d] = cosf(ang);
    sinb[s * HDIM + d] = sinf(ang);
}

// ---------------- RoPE apply (in-place on q and k, bf16) ----------------
__global__ __launch_bounds__(256) void rope_apply_k(bf16_t* __restrict__ q,
                                                    bf16_t* __restrict__ k,
                                                    const float* __restrict__ cosb,
                                                    const float* __restrict__ sinb) {
    int t = blockIdx.x * 256 + threadIdx.x;   // [0, M*H*64)
    int j = t & 63;
    int h = (t >> 6) & 15;
    int m = t >> 10;          // 0..4095
    int s = m & (SS - 1);
    size_t idx = (size_t)m * DD + h * HDIM + j;
    float c = cosb[s * HDIM + j];
    float sn = sinb[s * HDIM + j];
    float q1 = (float)q[idx], q2 = (float)q[idx + 64];
    q[idx]      = (bf16_t)(q1 * c - q2 * sn);
    q[idx + 64] = (bf16_t)(q2 * c + q1 * sn);
    float k1 = (float)k[idx], k2 = (float)k[idx + 64];
    k[idx]      = (bf16_t)(k1 * c - k2 * sn);
    k[idx + 64] = (bf16_t)(k2 * c + k1 * sn);
}

// ---------------- convert + transpose: W[K][N] f32 -> Wt[N][K] bf16 ----------------
__global__ __launch_bounds__(256) void convT_k(const float* __restrict__ W,
                                               bf16_t* __restrict__ Wt,
                                               int K, int N) {
    __shared__ float tile[32][33];
    int n0 = blockIdx.x * 32, k0 = blockIdx.y * 32;
    int tx = threadIdx.x & 31, ty = threadIdx.x >> 5;  // ty 0..7
    for (int i = 0; i < 4; ++i)
        tile[ty + 8 * i][tx] = W[(size_t)(k0 + ty + 8 * i) * N + n0 + tx];
    __syncthreads();
    for (int i = 0; i < 4; ++i)
        Wt[(size_t)(n0 + ty + 8 * i) * K + k0 + tx] = (bf16_t)tile[tx][ty + 8 * i];
}

// ---------------- V transpose: vb[b][s][hd] bf16 -> vtb[b][hd][s] bf16 ----------------
__global__ __launch_bounds__(256) void vtrans_k(const bf16_t* __restrict__ vbp,
                                                bf16_t* __restrict__ vtb) {
    __shared__ ushort tile[32][33];
    int b = blockIdx.z;
    int s0 = blockIdx.y * 32, c0 = blockIdx.x * 32;
    int tx = threadIdx.x & 31, ty = threadIdx.x >> 5;  // ty 0..7
    const ushort* in = (const ushort*)vbp + (size_t)b * SS * DD;
    ushort* out = (ushort*)vtb + (size_t)b * DD * SS;
    for (int i = 0; i < 4; ++i)
        tile[ty + 8 * i][tx] = in[(size_t)(s0 + ty + 8 * i) * DD + c0 + tx];
    __syncthreads();
    for (int i = 0; i < 4; ++i)
        out[(size_t)(c0 + ty + 8 * i) * SS + s0 + tx] = tile[tx][ty + 8 * i];
}

// ---------------- GEMM v4: fine-braided pipeline, BM=128 BN=256 BK=64, 8 waves ----------------
// Per-wave 64x64 out. Affinity staging: wave (wr,wc) stages A rows [wr*64+wc*16,+16)
// (2 loads) then B rows [wc*64+wr*32,+32) (4 loads) for K-step t+1, issued at P1 of step t.
// Counted waits (per-wave, own loads only):
//   mid (before post-MFMA1 barrier): wr==1 -> vmcnt(6)  [drains old B, lets the 6 new fly]
//   end (before post-MFMA2 barrier): wr==0 -> vmcnt(0); wr==1 -> vmcnt(4) [A landed, B deferred]
// B ni01 slices (staged by wr==0) are read at P1-next; B ni23 (staged by wr==1) at P2-next.
// EPI 0: bf16 store. EPI 1: f32 store = res + acc. EPI 2: bf16 = silu(gate)*acc.
template <int EPI>
__global__ __launch_bounds__(512, 1) void gemmF(const bf16_t* __restrict__ A,
                                                const bf16_t* __restrict__ Bt,
                                                void* __restrict__ outp,
                                                const float* __restrict__ res,
                                                const bf16_t* __restrict__ gate,
                                                int M, int NB, int Nout, int K) {
    __shared__ __align__(16) bf16_t ldsA[2][128 * 64];
    __shared__ __align__(16) bf16_t ldsB[2][256 * 64];
    int tid = threadIdx.x, lane = tid & 63, w = tid >> 6;
    int lr = lane & 15, lg = lane >> 4;
    int wr = w >> 2, wc = w & 3;   // 2(M) x 4(N), per-wave 64x64

    // T1: XCD-bijective swizzle, bx-major chunks
    int nwg = gridDim.x;
    int qc = nwg >> 3, rc = nwg & 7;
    int xcd = blockIdx.x & 7, jj = blockIdx.x >> 3;
    int wg = (xcd < rc ? xcd * (qc + 1) : rc * (qc + 1) + (xcd - rc) * qc) + jj;
    int GY = M >> 7;
    int bx = wg / GY, by = wg % GY;
    int m0 = by * 128, n0 = bx * 256;

    // affinity staging sources (pre-swizzled), LDS bases wave-uniform
    const bf16_t* aS[2]; const bf16_t* bS[4];
    int aO[2], bO[4];
    #pragma unroll
    for (int i = 0; i < 2; ++i) {
        int si = i * 64 + lane;
        int row = wr * 64 + wc * 16 + (si >> 3);
        int slot = si & 7;
        aS[i] = A + (size_t)(m0 + row) * K + ((slot ^ (row & 7)) * 8);
        aO[i] = (wr * 64 + wc * 16) * 64 + i * 512;
    }
    #pragma unroll
    for (int i = 0; i < 4; ++i) {
        int si = i * 64 + lane;
        int row = wc * 64 + wr * 32 + (si >> 3);
        int slot = si & 7;
        int rr = n0 + row; if (rr > NB - 1) rr = NB - 1;   // N-ragged clamp
        bS[i] = Bt + (size_t)rr * K + ((slot ^ (row & 7)) * 8);
        bO[i] = (wc * 64 + wr * 32) * 64 + i * 512;
    }

    auto stage = [&](int nb, int kt) {
        #pragma unroll
        for (int i = 0; i < 2; ++i) gload_lds16(aS[i] + kt, &ldsA[nb][aO[i]]);
        #pragma unroll
        for (int i = 0; i < 4; ++i) gload_lds16(bS[i] + kt, &ldsB[nb][bO[i]]);
    };

    int NT = K >> 6;
    f32x4 acc[4][4] = {};

    stage(0, 0);
    asm volatile("s_waitcnt vmcnt(0)" ::: "memory");
    __builtin_amdgcn_s_barrier();

    for (int t = 0; t < NT; ++t) {
        int cur = t & 1;
        const bf16_t* lA = ldsA[cur];
        const bf16_t* lB = ldsB[cur];
        MEMFENCE;
        // ---- P1: issue next-step stage, read A(all) + B(ni01) ----
        if (t + 1 < NT) stage(cur ^ 1, (t + 1) << 6);
        bf16x8 af[4][2], bf0[2][2];
        #pragma unroll
        for (int mi = 0; mi < 4; ++mi)
            #pragma unroll
            for (int kk = 0; kk < 2; ++kk) {
                int ra = wr * 64 + mi * 16 + lr;
                af[mi][kk] = *(const bf16x8*)(lA + ra * 64 + (((kk * 4 + lg) ^ (ra & 7)) * 8));
            }
        #pragma unroll
        for (int ni = 0; ni < 2; ++ni)
            #pragma unroll
            for (int kk = 0; kk < 2; ++kk) {
                int rb = wc * 64 + ni * 16 + lr;
                bf0[ni][kk] = *(const bf16x8*)(lB + rb * 64 + (((kk * 4 + lg) ^ (rb & 7)) * 8));
            }
        MEMFENCE;
        __builtin_amdgcn_s_barrier();
        __builtin_amdgcn_s_setprio(1);
        #pragma unroll
        for (int mi = 0; mi < 4; ++mi)
            #pragma unroll
            for (int ni = 0; ni < 2; ++ni)
                #pragma unroll
                for (int kk = 0; kk < 2; ++kk)
                    acc[mi][ni] = __builtin_amdgcn_mfma_f32_16x16x32_bf16(
                        af[mi][kk], bf0[ni][kk], acc[mi][ni], 0, 0, 0);
        __builtin_amdgcn_s_setprio(0);
        __builtin_amdgcn_sched_barrier(0);
        // mid wait: wr==1 drains its previous-step B slices (ni23 readers cross next barrier)
        if (wr == 1) {
            if (t + 1 < NT) asm volatile("s_waitcnt vmcnt(6)" ::: "memory");
            else            asm volatile("s_waitcnt vmcnt(0)" ::: "memory");
        }
        MEMFENCE;
        __builtin_amdgcn_s_barrier();
        MEMFENCE;
        // ---- P2: read B(ni23) ----
        bf16x8 bf1[2][2];
        #pragma unroll
        for (int ni = 0; ni < 2; ++ni)
            #pragma unroll
            for (int kk = 0; kk < 2; ++kk) {
                int rb = wc * 64 + (2 + ni) * 16 + lr;
                bf1[ni][kk] = *(const bf16x8*)(lB + rb * 64 + (((kk * 4 + lg) ^ (rb & 7)) * 8));
            }
        MEMFENCE;
        __builtin_amdgcn_s_barrier();
        __builtin_amdgcn_s_setprio(1);
        #pragma unroll
        for (int mi = 0; mi < 4; ++mi)
            #pragma unroll
            for (int ni = 0; ni < 2; ++ni)
                #pragma unroll
                for (int kk = 0; kk < 2; ++kk)
                    acc[mi][2 + ni] = __builtin_amdgcn_mfma_f32_16x16x32_bf16(
                        af[mi][kk], bf1[ni][kk], acc[mi][2 + ni], 0, 0, 0);
        __builtin_amdgcn_s_setprio(0);
        __builtin_amdgcn_sched_barrier(0);
        // end wait: wr==0 needs all 6 own loads (A + B-ni01) landed; wr==1 only A (first 2)
        if (wr == 0) asm volatile("s_waitcnt vmcnt(0)" ::: "memory");
        else         asm volatile("s_waitcnt vmcnt(4)" ::: "memory");
        MEMFENCE;
        __builtin_amdgcn_s_barrier();
    }

    #pragma unroll
    for (int mi = 0; mi < 4; ++mi) {
        int mbase = m0 + wr * 64 + mi * 16 + lg * 4;
        #pragma unroll
        for (int ni = 0; ni < 4; ++ni) {
            int n = n0 + wc * 64 + ni * 16 + lr;
            if (n < Nout) {
                f32x4 v = acc[mi][ni];
                #pragma unroll
                for (int r = 0; r < 4; ++r) {
                    size_t idx = (size_t)(mbase + r) * Nout + n;
                    if (EPI == 0) {
                        ((bf16_t*)outp)[idx] = (bf16_t)v[r];
                    } else if (EPI == 1) {
                        ((float*)outp)[idx] = res[idx] + v[r];
                    } else {
                        float g = (float)gate[idx];
                        float sg = g / (1.0f + __expf(-g));
                        ((bf16_t*)outp)[idx] = (bf16_t)(sg * v[r]);
                    }
                }
            }
        }
    }
}

// ---------------- Flash attention (causal), KVBLK=64, V pre-transposed ----------------
__global__ __launch_bounds__(256, 3) void attn_k(const bf16_t* __restrict__ qb,
                                                 const bf16_t* __restrict__ kb,
                                                 const bf16_t* __restrict__ vtb,
                                                 bf16_t* __restrict__ ab) {
    __shared__ __align__(16) bf16_t ldsK[64 * 128];   // [k][d], 16B slots src-swizzled
    __shared__ __align__(16) bf16_t ldsVt[128 * 64];  // [d][k], 16B slots src-swizzled
    __shared__ __align__(16) float pbuf[4][16][68];   // per wave: [q][k 0..63] 4-col swizzled
    int bid = blockIdx.x;
    int band = 31 - (bid >> 5);      // heavy bands dispatched first
    int bh = bid & 31;
    int b = bh >> 4, h = bh & 15;
    int q0 = band * 64;
    int tid = threadIdx.x, lane = tid & 63, w = tid >> 6;
    int lr = lane & 15, lg = lane >> 4;
    size_t kqbase = ((size_t)b * SS) * DD + h * HDIM;
    size_t vtbase = ((size_t)(b * HH + h)) * HDIM * SS;
    int qw = q0 + w * 16;

    bf16x8 aq[4];
    #pragma unroll
    for (int kd = 0; kd < 4; ++kd)
        aq[kd] = *(const bf16x8*)(qb + kqbase + (size_t)(qw + lr) * DD + kd * 32 + lg * 8);

    f32x4 acc[8] = {};
    float mrun[4], lrun[4];
    #pragma unroll
    for (int r = 0; r < 4; ++r) { mrun[r] = -1e30f; lrun[r] = 0.f; }
    const float scale = 0.08838834764831845f;  // 1/sqrt(128)

    for (int t = 0; t <= band; ++t) {
        int kk0 = t * 64;
        #pragma unroll
        for (int it = 0; it < 4; ++it) {
            int cid = it * 256 + tid;
            int kr = cid >> 4, kslot = cid & 15;
            gload_lds16(kb + kqbase + (size_t)(kk0 + kr) * DD + ((kslot ^ (kr & 7)) * 8),
                        ldsK + it * 2048 + w * 512);
            int vd = cid >> 3, vslot = cid & 7;
            gload_lds16(vtb + vtbase + (size_t)vd * SS + kk0 + ((vslot ^ (vd & 7)) * 8),
                        ldsVt + it * 2048 + w * 512);
        }
        asm volatile("s_waitcnt vmcnt(0)" ::: "memory");
        __syncthreads();

        // QK^T: S[q 16][k 64]
        f32x4 sf[4];
        #pragma unroll
        for (int nf = 0; nf < 4; ++nf) {
            f32x4 d = {};
            int row = nf * 16 + lr;
            #pragma unroll
            for (int kd = 0; kd < 4; ++kd) {
                bf16x8 bk = *(const bf16x8*)(ldsK + row * 128 +
                                             (((kd * 4 + lg) ^ (lr & 7)) * 8));
                d = __builtin_amdgcn_mfma_f32_16x16x32_bf16(aq[kd], bk, d, 0, 0, 0);
            }
            sf[nf] = d;
        }
        float corr[4];
        #pragma unroll
        for (int r = 0; r < 4; ++r) {
            int qg = qw + lg * 4 + r;
            float s[4];
            #pragma unroll
            for (int nf = 0; nf < 4; ++nf) {
                s[nf] = sf[nf][r] * scale;
                if (kk0 + nf * 16 + lr > qg) s[nf] = -1e30f;
            }
            float mx = fmaxf(fmaxf(s[0], s[1]), fmaxf(s[2], s[3]));
            mx = fmaxf(mx, __shfl_xor(mx, 1));
            mx = fmaxf(mx, __shfl_xor(mx, 2));
            mx = fmaxf(mx, __shfl_xor(mx, 4));
            mx = fmaxf(mx, __shfl_xor(mx, 8));
            float mnew = fmaxf(mrun[r], mx);
            float rs = 0.f;
            #pragma unroll
            for (int nf = 0; nf < 4; ++nf) {
                float p = __expf(s[nf] - mnew);
                rs += p;
                pbuf[w][lg * 4 + r][nf * 16 + (lr ^ (r << 2))] = p;
            }
            rs += __shfl_xor(rs, 1); rs += __shfl_xor(rs, 2);
            rs += __shfl_xor(rs, 4); rs += __shfl_xor(rs, 8);
            corr[r] = __expf(mrun[r] - mnew);
            lrun[r] = lrun[r] * corr[r] + rs;
            mrun[r] = mnew;
        }
        #pragma unroll
        for (int df = 0; df < 8; ++df)
            #pragma unroll
            for (int r = 0; r < 4; ++r) acc[df][r] *= corr[r];
        asm volatile("s_waitcnt lgkmcnt(0)" ::: "memory");
        // PV: two K=32 steps; A-frag rebuilt from pbuf (wave-local)
        #pragma unroll
        for (int ks2 = 0; ks2 < 2; ++ks2) {
            int nfA = ks2 * 2 + (lg >> 1);
            int off = (lg & 1) * 8;
            int sw = (lr & 3) << 2;
            float4 a0 = *(const float4*)&pbuf[w][lr][nfA * 16 + (off ^ sw)];
            float4 a1 = *(const float4*)&pbuf[w][lr][nfA * 16 + ((off + 4) ^ sw)];
            bf16x8 ap;
            ap[0] = (bf16_t)a0.x; ap[1] = (bf16_t)a0.y;
            ap[2] = (bf16_t)a0.z; ap[3] = (bf16_t)a0.w;
            ap[4] = (bf16_t)a1.x; ap[5] = (bf16_t)a1.y;
            ap[6] = (bf16_t)a1.z; ap[7] = (bf16_t)a1.w;
            #pragma unroll
            for (int df = 0; df < 8; ++df) {
                bf16x8 bv = *(const bf16x8*)(ldsVt + (df * 16 + lr) * 64 +
                                             (((ks2 * 4 + lg) ^ (lr & 7)) * 8));
                acc[df] = __builtin_amdgcn_mfma_f32_16x16x32_bf16(ap, bv, acc[df], 0, 0, 0);
            }
        }
        __syncthreads();
    }
    #pragma unroll
    for (int df = 0; df < 8; ++df)
        #pragma unroll
        for (int r = 0; r < 4; ++r) {
            int qg = qw + lg * 4 + r;
            ab[kqbase + (size_t)qg * DD + df * 16 + lr] = (bf16_t)(acc[df][r] / lrun[r]);
        }
}

extern "C" void kernel_launch(void* const* d_in, const int* in_sizes, int n_in,
                              void* d_out, int out_size, void* d_ws, size_t ws_size,
                              hipStream_t stream) {
    const float* hs  = (const float*)d_in[0];
    // d_in[1] = attention_mask (exactly causal) — applied analytically
    const float* Wq  = (const float*)d_in[2];
    const float* Wk  = (const float*)d_in[3];
    const float* Wv  = (const float*)d_in[4];
    const float* Wo  = (const float*)d_in[5];
    const float* Wg  = (const float*)d_in[6];
    const float* Wu  = (const float*)d_in[7];
    const float* Wd  = (const float*)d_in[8];
    const float* ln1 = (const float*)d_in[9];
    const float* ln2 = (const float*)d_in[10];

    char* ws = (char*)d_ws;
    const size_t MB = 1u << 20;
    bf16_t* xb     = (bf16_t*)(ws);                 // 16 MiB [M][D]
    bf16_t* qb     = (bf16_t*)(ws + 16 * MB);       // 16 MiB
    bf16_t* kb     = (bf16_t*)(ws + 32 * MB);       // 16 MiB
    bf16_t* vb     = (bf16_t*)(ws + 48 * MB);       // 16 MiB
    float*  hidden = (float*)(ws + 64 * MB);        // 32 MiB [M][D] f32 (written at Wo step)
    bf16_t* vtb    = (bf16_t*)(ws + 64 * MB);       // 16 MiB — dead before 'hidden' is written
    float*  cosb   = (float*)(ws + 96 * MB);        // 1 MiB
    float*  sinb   = (float*)(ws + 97 * MB);        // 1 MiB
    bf16_t* wt     = (bf16_t*)(ws + 98 * MB);       // 21.5 MiB transposed-weight scratch
    bf16_t* ab = xb;   // attn out reuses xb
    bf16_t* yb = xb;   // ln2 out reuses xb
    bf16_t* gb = qb;   // gate/h [M][I] = 43 MiB, reuses q/k/v region

    if (ws_size < (size_t)(98 * MB) + (size_t)II * DD * 2) return;

    const int GY  = MM / 128;                  // 32
    const int NXQ = DD / 256;                  // 8  -> grid 256 (full pack)
    const int NXI = (II + 255) / 256;          // 22 -> grid 704 (92% pack)

    // 1. LN1
    rmsnorm_k<<<MM, 256, 0, stream>>>(hs, ln1, xb);
    // 2. RoPE tables
    rope_tables_k<<<SS, 128, 0, stream>>>(cosb, sinb);
    // 3-8. QKV projections
    convT_k<<<dim3(DD / 32, DD / 32), 256, 0, stream>>>(Wq, wt, DD, DD);
    gemmF<0><<<GY * NXQ, 512, 0, stream>>>(xb, wt, qb, nullptr, nullptr, MM, DD, DD, DD);
    convT_k<<<dim3(DD / 32, DD / 32), 256, 0, stream>>>(Wk, wt, DD, DD);
    gemmF<0><<<GY * NXQ, 512, 0, stream>>>(xb, wt, kb, nullptr, nullptr, MM, DD, DD, DD);
    convT_k<<<dim3(DD / 32, DD / 32), 256, 0, stream>>>(Wv, wt, DD, DD);
    gemmF<0><<<GY * NXQ, 512, 0, stream>>>(xb, wt, vb, nullptr, nullptr, MM, DD, DD, DD);
    // 9. V transpose for attention B-operand staging
    vtrans_k<<<dim3(DD / 32, SS / 32, BB), 256, 0, stream>>>(vb, vtb);
    // 10. RoPE on q,k
    rope_apply_k<<<(MM * HH * 64) / 256, 256, 0, stream>>>(qb, kb, cosb, sinb);
    // 11. attention
    attn_k<<<1024, 256, 0, stream>>>(qb, kb, vtb, ab);
    // 12-13. Wo + residual -> hidden (f32)
    convT_k<<<dim3(DD / 32, DD / 32), 256, 0, stream>>>(Wo, wt, DD, DD);
    gemmF<1><<<GY * NXQ, 512, 0, stream>>>(ab, wt, hidden, hs, nullptr, MM, DD, DD, DD);
    // 14. LN2
    rmsnorm_k<<<MM, 256, 0, stream>>>(hidden, ln2, yb);
    // 15-16. gate = y @ Wg
    convT_k<<<dim3(II / 32, DD / 32), 256, 0, stream>>>(Wg, wt, DD, II);
    gemmF<0><<<GY * NXI, 512, 0, stream>>>(yb, wt, gb, nullptr, nullptr, MM, II, II, DD);
    // 17-18. up = y @ Wu, fused h = silu(gate)*up -> gb
    convT_k<<<dim3(II / 32, DD / 32), 256, 0, stream>>>(Wu, wt, DD, II);
    gemmF<2><<<GY * NXI, 512, 0, stream>>>(yb, wt, gb, nullptr, gb, MM, II, II, DD);
    // 19-20. out = hidden + h @ Wd (f32)
    convT_k<<<dim3(DD / 32, II / 32), 256, 0, stream>>>(Wd, wt, II, DD);
    gemmF<1><<<GY * NXQ, 512, 0, stream>>>(gb, wt, (float*)d_out, hidden, nullptr, MM, DD, DD, II);
}

// Round 8
// 687.813 us; speedup vs baseline: 1.3377x; 1.3377x over previous
//
#include <hip/hip_runtime.h>
#include <hip/hip_bf16.h>
#include <cmath>

typedef __bf16 bf16_t;
typedef __bf16 bf16x8 __attribute__((ext_vector_type(8)));
typedef float f32x4 __attribute__((ext_vector_type(4)));

#define DEV __device__ __forceinline__

static constexpr int BB = 2, SS = 2048, DD = 2048, HH = 16, HDIM = 128, II = 5504;
static constexpr int MM = BB * SS; // 4096

DEV void gload_lds16(const void* g, void* l) {
    __builtin_amdgcn_global_load_lds(
        (__attribute__((address_space(1))) void*)const_cast<void*>(g),
        (__attribute__((address_space(3))) void*)l, 16, 0, 0);
}

// ---------------- RMSNorm: f32 in -> bf16 out ----------------
__global__ __launch_bounds__(256) void rmsnorm_k(const float* __restrict__ x,
                                                 const float* __restrict__ w,
                                                 bf16_t* __restrict__ out) {
    int row = blockIdx.x;
    int t = threadIdx.x;
    const float4* xr = (const float4*)(x + (size_t)row * DD);
    float4 a = xr[t];
    float4 b = xr[t + 256];
    float ss = a.x * a.x + a.y * a.y + a.z * a.z + a.w * a.w +
               b.x * b.x + b.y * b.y + b.z * b.z + b.w * b.w;
    for (int m = 1; m < 64; m <<= 1) ss += __shfl_xor(ss, m);
    __shared__ float red[4];
    int lane = t & 63, wv = t >> 6;
    if (lane == 0) red[wv] = ss;
    __syncthreads();
    float scale = rsqrtf((red[0] + red[1] + red[2] + red[3]) * (1.0f / DD) + 1e-6f);
    const float4* w4 = (const float4*)w;
    float4 wa = w4[t], wb = w4[t + 256];
    bf16_t* o = out + (size_t)row * DD;
    union { bf16_t h[4]; ushort4 u; } pa, pb;
    pa.h[0] = (bf16_t)(a.x * scale * wa.x); pa.h[1] = (bf16_t)(a.y * scale * wa.y);
    pa.h[2] = (bf16_t)(a.z * scale * wa.z); pa.h[3] = (bf16_t)(a.w * scale * wa.w);
    pb.h[0] = (bf16_t)(b.x * scale * wb.x); pb.h[1] = (bf16_t)(b.y * scale * wb.y);
    pb.h[2] = (bf16_t)(b.z * scale * wb.z); pb.h[3] = (bf16_t)(b.w * scale * wb.w);
    ((ushort4*)o)[t] = pa.u;
    ((ushort4*)o)[t + 256] = pb.u;
}

// ---------------- RoPE tables ----------------
__global__ void rope_tables_k(float* __restrict__ cosb, float* __restrict__ sinb) {
    int s = blockIdx.x;
    int d = threadIdx.x;       // 0..127
    int j = d & 63;
    float inv = powf(10000.0f, -(2.0f * (float)j) / 128.0f);
    float ang = (float)s * inv;
    cosb[s * HDIM + d] = cosf(ang);
    sinb[s * HDIM + d] = sinf(ang);
}

// ---------------- RoPE apply (in-place on q and k, bf16) ----------------
__global__ __launch_bounds__(256) void rope_apply_k(bf16_t* __restrict__ q,
                                                    bf16_t* __restrict__ k,
                                                    const float* __restrict__ cosb,
                                                    const float* __restrict__ sinb) {
    int t = blockIdx.x * 256 + threadIdx.x;   // [0, M*H*64)
    int j = t & 63;
    int h = (t >> 6) & 15;
    int m = t >> 10;          // 0..4095
    int s = m & (SS - 1);
    size_t idx = (size_t)m * DD + h * HDIM + j;
    float c = cosb[s * HDIM + j];
    float sn = sinb[s * HDIM + j];
    float q1 = (float)q[idx], q2 = (float)q[idx + 64];
    q[idx]      = (bf16_t)(q1 * c - q2 * sn);
    q[idx + 64] = (bf16_t)(q2 * c + q1 * sn);
    float k1 = (float)k[idx], k2 = (float)k[idx + 64];
    k[idx]      = (bf16_t)(k1 * c - k2 * sn);
    k[idx + 64] = (bf16_t)(k2 * c + k1 * sn);
}

// ---------------- convert + transpose: W[K][N] f32 -> Wt[N][K] bf16 ----------------
__global__ __launch_bounds__(256) void convT_k(const float* __restrict__ W,
                                               bf16_t* __restrict__ Wt,
                                               int K, int N) {
    __shared__ float tile[32][33];
    int n0 = blockIdx.x * 32, k0 = blockIdx.y * 32;
    int tx = threadIdx.x & 31, ty = threadIdx.x >> 5;  // ty 0..7
    for (int i = 0; i < 4; ++i)
        tile[ty + 8 * i][tx] = W[(size_t)(k0 + ty + 8 * i) * N + n0 + tx];
    __syncthreads();
    for (int i = 0; i < 4; ++i)
        Wt[(size_t)(n0 + ty + 8 * i) * K + k0 + tx] = (bf16_t)tile[tx][ty + 8 * i];
}

// ---------------- V transpose: vb[b][s][hd] bf16 -> vtb[b][hd][s] bf16 ----------------
__global__ __launch_bounds__(256) void vtrans_k(const bf16_t* __restrict__ vbp,
                                                bf16_t* __restrict__ vtb) {
    __shared__ ushort tile[32][33];
    int b = blockIdx.z;
    int s0 = blockIdx.y * 32, c0 = blockIdx.x * 32;
    int tx = threadIdx.x & 31, ty = threadIdx.x >> 5;  // ty 0..7
    const ushort* in = (const ushort*)vbp + (size_t)b * SS * DD;
    ushort* out = (ushort*)vtb + (size_t)b * DD * SS;
    for (int i = 0; i < 4; ++i)
        tile[ty + 8 * i][tx] = in[(size_t)(s0 + ty + 8 * i) * DD + c0 + tx];
    __syncthreads();
    for (int i = 0; i < 4; ++i)
        out[(size_t)(c0 + ty + 8 * i) * SS + s0 + tx] = tile[tx][ty + 8 * i];
}

// ---------------- GEMM: minimum-2-phase (T3 catalog m248v2 recipe) ----------------
// C[M][N] = A[M][K] * Bt[N][K]^T, bf16 in, f32 acc. 128x128 tile, BK=64, 4 waves.
// Double-buffered LDS; stage(t+1) issued BEFORE reading buf[t] (loads covered by the
// frag-read+MFMA phase); ONE __syncthreads per K-step (its vmcnt drain lands the
// prefetch, its barrier frees the other buffer). T1 XCD swizzle retained.
// EPI 0: bf16 store. EPI 1: f32 store = res + acc. EPI 2: bf16 = silu(gate)*acc.
template <int EPI>
__global__ __launch_bounds__(256, 2) void gemm_bt(const bf16_t* __restrict__ A,
                                                  const bf16_t* __restrict__ Bt,
                                                  void* __restrict__ outp,
                                                  const float* __restrict__ res,
                                                  const bf16_t* __restrict__ gate,
                                                  int M, int N, int K) {
    __shared__ __align__(16) bf16_t ldsA[2][128 * 64];
    __shared__ __align__(16) bf16_t ldsB[2][128 * 64];
    int tid = threadIdx.x, lane = tid & 63, w = tid >> 6;
    int lr = lane & 15, lg = lane >> 4;

    // T1: XCD-bijective swizzle, bx-major within each XCD chunk
    int GX = gridDim.x, GYd = gridDim.y;
    int bid = blockIdx.y * GX + blockIdx.x;
    int nwg = GX * GYd;
    int qc = nwg >> 3, rc = nwg & 7;
    int xcd = bid & 7, jj = bid >> 3;
    int wg = (xcd < rc ? xcd * (qc + 1) : rc * (qc + 1) + (xcd - rc) * qc) + jj;
    int bx = wg / GYd;
    int by = wg % GYd;

    int m0 = by * 128, n0 = bx * 128;
    int wr = w >> 1, wc = w & 1;
    f32x4 acc[4][4] = {};
    int srow = w * 8 + (lane >> 3);  // 0..31
    int sslot = lane & 7;

    auto stage = [&](int nb, int kt) {
        #pragma unroll
        for (int i = 0; i < 4; ++i) {
            int row = i * 32 + srow;
            int sp = sslot ^ (row & 7);
            gload_lds16(A + (size_t)(m0 + row) * K + kt + sp * 8,
                        &ldsA[nb][i * 2048 + w * 512]);
            gload_lds16(Bt + (size_t)(n0 + row) * K + kt + sp * 8,
                        &ldsB[nb][i * 2048 + w * 512]);
        }
    };

    int NT = K >> 6;
    stage(0, 0);
    __syncthreads();   // drain prologue stage

    for (int tt = 0; tt < NT; ++tt) {
        int cur = tt & 1;
        // issue next tile's loads first — covered by this tile's reads+MFMA
        if (tt + 1 < NT) stage(cur ^ 1, (tt + 1) << 6);
        const bf16_t* lA = ldsA[cur];
        const bf16_t* lB = ldsB[cur];
        #pragma unroll
        for (int kk = 0; kk < 2; ++kk) {
            bf16x8 af[4], bfm[4];
            #pragma unroll
            for (int x = 0; x < 4; ++x) {
                int ra = wr * 64 + x * 16 + lr;
                int sa = (kk * 4 + lg) ^ (ra & 7);
                af[x] = *(const bf16x8*)(lA + ra * 64 + sa * 8);
                int rb = wc * 64 + x * 16 + lr;
                int sb = (kk * 4 + lg) ^ (rb & 7);
                bfm[x] = *(const bf16x8*)(lB + rb * 64 + sb * 8);
            }
            __builtin_amdgcn_s_setprio(1);
            #pragma unroll
            for (int mi = 0; mi < 4; ++mi)
                #pragma unroll
                for (int ni = 0; ni < 4; ++ni)
                    acc[mi][ni] = __builtin_amdgcn_mfma_f32_16x16x32_bf16(
                        af[mi], bfm[ni], acc[mi][ni], 0, 0, 0);
            __builtin_amdgcn_s_setprio(0);
        }
        __syncthreads();  // single drain+barrier per K-step: prefetch landed, buffer freed
    }

    #pragma unroll
    for (int mi = 0; mi < 4; ++mi) {
        int mbase = m0 + wr * 64 + mi * 16 + lg * 4;
        #pragma unroll
        for (int ni = 0; ni < 4; ++ni) {
            int n = n0 + wc * 64 + ni * 16 + lr;
            f32x4 v = acc[mi][ni];
            #pragma unroll
            for (int r = 0; r < 4; ++r) {
                size_t idx = (size_t)(mbase + r) * N + n;
                if (EPI == 0) {
                    ((bf16_t*)outp)[idx] = (bf16_t)v[r];
                } else if (EPI == 1) {
                    ((float*)outp)[idx] = res[idx] + v[r];
                } else {
                    float g = (float)gate[idx];
                    float sg = g / (1.0f + __expf(-g));
                    ((bf16_t*)outp)[idx] = (bf16_t)(sg * v[r]);
                }
            }
        }
    }
}

// ---------------- Flash attention (causal), KVBLK=64, V pre-transposed ----------------
__global__ __launch_bounds__(256, 3) void attn_k(const bf16_t* __restrict__ qb,
                                                 const bf16_t* __restrict__ kb,
                                                 const bf16_t* __restrict__ vtb,
                                                 bf16_t* __restrict__ ab) {
    __shared__ __align__(16) bf16_t ldsK[64 * 128];   // [k][d], 16B slots src-swizzled
    __shared__ __align__(16) bf16_t ldsVt[128 * 64];  // [d][k], 16B slots src-swizzled
    __shared__ __align__(16) float pbuf[4][16][68];   // per wave: [q][k 0..63] 4-col swizzled
    int bid = blockIdx.x;
    int band = 31 - (bid >> 5);      // heavy bands dispatched first
    int bh = bid & 31;
    int b = bh >> 4, h = bh & 15;
    int q0 = band * 64;
    int tid = threadIdx.x, lane = tid & 63, w = tid >> 6;
    int lr = lane & 15, lg = lane >> 4;
    size_t kqbase = ((size_t)b * SS) * DD + h * HDIM;
    size_t vtbase = ((size_t)(b * HH + h)) * HDIM * SS;
    int qw = q0 + w * 16;

    bf16x8 aq[4];
    #pragma unroll
    for (int kd = 0; kd < 4; ++kd)
        aq[kd] = *(const bf16x8*)(qb + kqbase + (size_t)(qw + lr) * DD + kd * 32 + lg * 8);

    f32x4 acc[8] = {};
    float mrun[4], lrun[4];
    #pragma unroll
    for (int r = 0; r < 4; ++r) { mrun[r] = -1e30f; lrun[r] = 0.f; }
    const float scale = 0.08838834764831845f;  // 1/sqrt(128)

    for (int t = 0; t <= band; ++t) {
        int kk0 = t * 64;
        #pragma unroll
        for (int it = 0; it < 4; ++it) {
            int cid = it * 256 + tid;
            int kr = cid >> 4, kslot = cid & 15;
            gload_lds16(kb + kqbase + (size_t)(kk0 + kr) * DD + ((kslot ^ (kr & 7)) * 8),
                        ldsK + it * 2048 + w * 512);
            int vd = cid >> 3, vslot = cid & 7;
            gload_lds16(vtb + vtbase + (size_t)vd * SS + kk0 + ((vslot ^ (vd & 7)) * 8),
                        ldsVt + it * 2048 + w * 512);
        }
        asm volatile("s_waitcnt vmcnt(0)" ::: "memory");
        __syncthreads();

        // QK^T: S[q 16][k 64]
        f32x4 sf[4];
        #pragma unroll
        for (int nf = 0; nf < 4; ++nf) {
            f32x4 d = {};
            int row = nf * 16 + lr;
            #pragma unroll
            for (int kd = 0; kd < 4; ++kd) {
                bf16x8 bk = *(const bf16x8*)(ldsK + row * 128 +
                                             (((kd * 4 + lg) ^ (lr & 7)) * 8));
                d = __builtin_amdgcn_mfma_f32_16x16x32_bf16(aq[kd], bk, d, 0, 0, 0);
            }
            sf[nf] = d;
        }
        float corr[4];
        #pragma unroll
        for (int r = 0; r < 4; ++r) {
            int qg = qw + lg * 4 + r;
            float s[4];
            #pragma unroll
            for (int nf = 0; nf < 4; ++nf) {
                s[nf] = sf[nf][r] * scale;
                if (kk0 + nf * 16 + lr > qg) s[nf] = -1e30f;
            }
            float mx = fmaxf(fmaxf(s[0], s[1]), fmaxf(s[2], s[3]));
            mx = fmaxf(mx, __shfl_xor(mx, 1));
            mx = fmaxf(mx, __shfl_xor(mx, 2));
            mx = fmaxf(mx, __shfl_xor(mx, 4));
            mx = fmaxf(mx, __shfl_xor(mx, 8));
            float mnew = fmaxf(mrun[r], mx);
            float rs = 0.f;
            #pragma unroll
            for (int nf = 0; nf < 4; ++nf) {
                float p = __expf(s[nf] - mnew);
                rs += p;
                pbuf[w][lg * 4 + r][nf * 16 + (lr ^ (r << 2))] = p;
            }
            rs += __shfl_xor(rs, 1); rs += __shfl_xor(rs, 2);
            rs += __shfl_xor(rs, 4); rs += __shfl_xor(rs, 8);
            corr[r] = __expf(mrun[r] - mnew);
            lrun[r] = lrun[r] * corr[r] + rs;
            mrun[r] = mnew;
        }
        #pragma unroll
        for (int df = 0; df < 8; ++df)
            #pragma unroll
            for (int r = 0; r < 4; ++r) acc[df][r] *= corr[r];
        asm volatile("s_waitcnt lgkmcnt(0)" ::: "memory");
        // PV: two K=32 steps; A-frag rebuilt from pbuf (wave-local)
        #pragma unroll
        for (int ks2 = 0; ks2 < 2; ++ks2) {
            int nfA = ks2 * 2 + (lg >> 1);
            int off = (lg & 1) * 8;
            int sw = (lr & 3) << 2;
            float4 a0 = *(const float4*)&pbuf[w][lr][nfA * 16 + (off ^ sw)];
            float4 a1 = *(const float4*)&pbuf[w][lr][nfA * 16 + ((off + 4) ^ sw)];
            bf16x8 ap;
            ap[0] = (bf16_t)a0.x; ap[1] = (bf16_t)a0.y;
            ap[2] = (bf16_t)a0.z; ap[3] = (bf16_t)a0.w;
            ap[4] = (bf16_t)a1.x; ap[5] = (bf16_t)a1.y;
            ap[6] = (bf16_t)a1.z; ap[7] = (bf16_t)a1.w;
            #pragma unroll
            for (int df = 0; df < 8; ++df) {
                bf16x8 bv = *(const bf16x8*)(ldsVt + (df * 16 + lr) * 64 +
                                             (((ks2 * 4 + lg) ^ (lr & 7)) * 8));
                acc[df] = __builtin_amdgcn_mfma_f32_16x16x32_bf16(ap, bv, acc[df], 0, 0, 0);
            }
        }
        __syncthreads();
    }
    #pragma unroll
    for (int df = 0; df < 8; ++df)
        #pragma unroll
        for (int r = 0; r < 4; ++r) {
            int qg = qw + lg * 4 + r;
            ab[kqbase + (size_t)qg * DD + df * 16 + lr] = (bf16_t)(acc[df][r] / lrun[r]);
        }
}

extern "C" void kernel_launch(void* const* d_in, const int* in_sizes, int n_in,
                              void* d_out, int out_size, void* d_ws, size_t ws_size,
                              hipStream_t stream) {
    const float* hs  = (const float*)d_in[0];
    // d_in[1] = attention_mask (exactly causal) — applied analytically
    const float* Wq  = (const float*)d_in[2];
    const float* Wk  = (const float*)d_in[3];
    const float* Wv  = (const float*)d_in[4];
    const float* Wo  = (const float*)d_in[5];
    const float* Wg  = (const float*)d_in[6];
    const float* Wu  = (const float*)d_in[7];
    const float* Wd  = (const float*)d_in[8];
    const float* ln1 = (const float*)d_in[9];
    const float* ln2 = (const float*)d_in[10];

    char* ws = (char*)d_ws;
    const size_t MB = 1u << 20;
    bf16_t* xb     = (bf16_t*)(ws);                 // 16 MiB [M][D]
    bf16_t* qb     = (bf16_t*)(ws + 16 * MB);       // 16 MiB
    bf16_t* kb     = (bf16_t*)(ws + 32 * MB);       // 16 MiB
    bf16_t* vb     = (bf16_t*)(ws + 48 * MB);       // 16 MiB
    float*  hidden = (float*)(ws + 64 * MB);        // 32 MiB [M][D] f32 (written at Wo step)
    bf16_t* vtb    = (bf16_t*)(ws + 64 * MB);       // 16 MiB — dead before 'hidden' is written
    float*  cosb   = (float*)(ws + 96 * MB);        // 1 MiB
    float*  sinb   = (float*)(ws + 97 * MB);        // 1 MiB
    bf16_t* wt     = (bf16_t*)(ws + 98 * MB);       // 21.5 MiB transposed-weight scratch
    bf16_t* ab = xb;   // attn out reuses xb
    bf16_t* yb = xb;   // ln2 out reuses xb
    bf16_t* gb = qb;   // gate/h [M][I] = 43 MiB, reuses q/k/v region

    if (ws_size < (size_t)(98 * MB) + (size_t)II * DD * 2) return;

    // 1. LN1
    rmsnorm_k<<<MM, 256, 0, stream>>>(hs, ln1, xb);
    // 2. RoPE tables
    rope_tables_k<<<SS, 128, 0, stream>>>(cosb, sinb);
    // 3-8. QKV projections
    convT_k<<<dim3(DD / 32, DD / 32), 256, 0, stream>>>(Wq, wt, DD, DD);
    gemm_bt<0><<<dim3(DD / 128, MM / 128), 256, 0, stream>>>(xb, wt, qb, nullptr, nullptr, MM, DD, DD);
    convT_k<<<dim3(DD / 32, DD / 32), 256, 0, stream>>>(Wk, wt, DD, DD);
    gemm_bt<0><<<dim3(DD / 128, MM / 128), 256, 0, stream>>>(xb, wt, kb, nullptr, nullptr, MM, DD, DD);
    convT_k<<<dim3(DD / 32, DD / 32), 256, 0, stream>>>(Wv, wt, DD, DD);
    gemm_bt<0><<<dim3(DD / 128, MM / 128), 256, 0, stream>>>(xb, wt, vb, nullptr, nullptr, MM, DD, DD);
    // 9. V transpose for attention B-operand staging
    vtrans_k<<<dim3(DD / 32, SS / 32, BB), 256, 0, stream>>>(vb, vtb);
    // 10. RoPE on q,k
    rope_apply_k<<<(MM * HH * 64) / 256, 256, 0, stream>>>(qb, kb, cosb, sinb);
    // 11. attention
    attn_k<<<1024, 256, 0, stream>>>(qb, kb, vtb, ab);
    // 12-13. Wo + residual -> hidden (f32)
    convT_k<<<dim3(DD / 32, DD / 32), 256, 0, stream>>>(Wo, wt, DD, DD);
    gemm_bt<1><<<dim3(DD / 128, MM / 128), 256, 0, stream>>>(ab, wt, hidden, hs, nullptr, MM, DD, DD);
    // 14. LN2
    rmsnorm_k<<<MM, 256, 0, stream>>>(hidden, ln2, yb);
    // 15-16. gate = y @ Wg
    convT_k<<<dim3(II / 32, DD / 32), 256, 0, stream>>>(Wg, wt, DD, II);
    gemm_bt<0><<<dim3(II / 128, MM / 128), 256, 0, stream>>>(yb, wt, gb, nullptr, nullptr, MM, II, DD);
    // 17-18. up = y @ Wu, fused h = silu(gate)*up -> gb
    convT_k<<<dim3(II / 32, DD / 32), 256, 0, stream>>>(Wu, wt, DD, II);
    gemm_bt<2><<<dim3(II / 128, MM / 128), 256, 0, stream>>>(yb, wt, gb, nullptr, gb, MM, II, DD);
    // 19-20. out = hidden + h @ Wd (f32)
    convT_k<<<dim3(DD / 32, II / 32), 256, 0, stream>>>(Wd, wt, II, DD);
    gemm_bt<1><<<dim3(DD / 128, MM / 128), 256, 0, stream>>>(gb, wt, (float*)d_out, hidden, nullptr, MM, DD, II);
}

// Round 9
// 625.272 us; speedup vs baseline: 1.4715x; 1.1000x over previous
//
#include <hip/hip_runtime.h>
#include <hip/hip_bf16.h>
#include <cmath>

typedef __bf16 bf16_t;
typedef __bf16 bf16x8 __attribute__((ext_vector_type(8)));
typedef float f32x4 __attribute__((ext_vector_type(4)));

#define DEV __device__ __forceinline__

static constexpr int BB = 2, SS = 2048, DD = 2048, HH = 16, HDIM = 128, II = 5504;
static constexpr int MM = BB * SS; // 4096

DEV void gload_lds16(const void* g, void* l) {
    __builtin_amdgcn_global_load_lds(
        (__attribute__((address_space(1))) void*)const_cast<void*>(g),
        (__attribute__((address_space(3))) void*)l, 16, 0, 0);
}

// ---------------- RMSNorm: f32 in -> bf16 out ----------------
__global__ __launch_bounds__(256) void rmsnorm_k(const float* __restrict__ x,
                                                 const float* __restrict__ w,
                                                 bf16_t* __restrict__ out) {
    int row = blockIdx.x;
    int t = threadIdx.x;
    const float4* xr = (const float4*)(x + (size_t)row * DD);
    float4 a = xr[t];
    float4 b = xr[t + 256];
    float ss = a.x * a.x + a.y * a.y + a.z * a.z + a.w * a.w +
               b.x * b.x + b.y * b.y + b.z * b.z + b.w * b.w;
    for (int m = 1; m < 64; m <<= 1) ss += __shfl_xor(ss, m);
    __shared__ float red[4];
    int lane = t & 63, wv = t >> 6;
    if (lane == 0) red[wv] = ss;
    __syncthreads();
    float scale = rsqrtf((red[0] + red[1] + red[2] + red[3]) * (1.0f / DD) + 1e-6f);
    const float4* w4 = (const float4*)w;
    float4 wa = w4[t], wb = w4[t + 256];
    bf16_t* o = out + (size_t)row * DD;
    union { bf16_t h[4]; ushort4 u; } pa, pb;
    pa.h[0] = (bf16_t)(a.x * scale * wa.x); pa.h[1] = (bf16_t)(a.y * scale * wa.y);
    pa.h[2] = (bf16_t)(a.z * scale * wa.z); pa.h[3] = (bf16_t)(a.w * scale * wa.w);
    pb.h[0] = (bf16_t)(b.x * scale * wb.x); pb.h[1] = (bf16_t)(b.y * scale * wb.y);
    pb.h[2] = (bf16_t)(b.z * scale * wb.z); pb.h[3] = (bf16_t)(b.w * scale * wb.w);
    ((ushort4*)o)[t] = pa.u;
    ((ushort4*)o)[t + 256] = pb.u;
}

// ---------------- RoPE tables ----------------
__global__ void rope_tables_k(float* __restrict__ cosb, float* __restrict__ sinb) {
    int s = blockIdx.x;
    int d = threadIdx.x;       // 0..127
    int j = d & 63;
    float inv = powf(10000.0f, -(2.0f * (float)j) / 128.0f);
    float ang = (float)s * inv;
    cosb[s * HDIM + d] = cosf(ang);
    sinb[s * HDIM + d] = sinf(ang);
}

// ---------------- RoPE apply (in-place on q and k, bf16) ----------------
__global__ __launch_bounds__(256) void rope_apply_k(bf16_t* __restrict__ q,
                                                    bf16_t* __restrict__ k,
                                                    const float* __restrict__ cosb,
                                                    const float* __restrict__ sinb) {
    int t = blockIdx.x * 256 + threadIdx.x;   // [0, M*H*64)
    int j = t & 63;
    int h = (t >> 6) & 15;
    int m = t >> 10;          // 0..4095
    int s = m & (SS - 1);
    size_t idx = (size_t)m * DD + h * HDIM + j;
    float c = cosb[s * HDIM + j];
    float sn = sinb[s * HDIM + j];
    float q1 = (float)q[idx], q2 = (float)q[idx + 64];
    q[idx]      = (bf16_t)(q1 * c - q2 * sn);
    q[idx + 64] = (bf16_t)(q2 * c + q1 * sn);
    float k1 = (float)k[idx], k2 = (float)k[idx + 64];
    k[idx]      = (bf16_t)(k1 * c - k2 * sn);
    k[idx + 64] = (bf16_t)(k2 * c + k1 * sn);
}

// ---------------- convert + transpose: W[K][N] f32 -> Wt[N][K] bf16 ----------------
__global__ __launch_bounds__(256) void convT_k(const float* __restrict__ W,
                                               bf16_t* __restrict__ Wt,
                                               int K, int N) {
    __shared__ float tile[32][33];
    int n0 = blockIdx.x * 32, k0 = blockIdx.y * 32;
    int tx = threadIdx.x & 31, ty = threadIdx.x >> 5;  // ty 0..7
    for (int i = 0; i < 4; ++i)
        tile[ty + 8 * i][tx] = W[(size_t)(k0 + ty + 8 * i) * N + n0 + tx];
    __syncthreads();
    for (int i = 0; i < 4; ++i)
        Wt[(size_t)(n0 + ty + 8 * i) * K + k0 + tx] = (bf16_t)tile[tx][ty + 8 * i];
}

// ---------------- V transpose: vb[b][s][hd] bf16 -> vtb[b][hd][s] bf16 ----------------
__global__ __launch_bounds__(256) void vtrans_k(const bf16_t* __restrict__ vbp,
                                                bf16_t* __restrict__ vtb) {
    __shared__ ushort tile[32][33];
    int b = blockIdx.z;
    int s0 = blockIdx.y * 32, c0 = blockIdx.x * 32;
    int tx = threadIdx.x & 31, ty = threadIdx.x >> 5;  // ty 0..7
    const ushort* in = (const ushort*)vbp + (size_t)b * SS * DD;
    ushort* out = (ushort*)vtb + (size_t)b * DD * SS;
    for (int i = 0; i < 4; ++i)
        tile[ty + 8 * i][tx] = in[(size_t)(s0 + ty + 8 * i) * DD + c0 + tx];
    __syncthreads();
    for (int i = 0; i < 4; ++i)
        out[(size_t)(c0 + ty + 8 * i) * SS + s0 + tx] = tile[tx][ty + 8 * i];
}

// ---------------- GEMM (r5-proven): C[M][N] = A[M][K] * Bt[N][K]^T ----------------
// EPI 0: bf16 store. EPI 1: f32 store = res + acc.
template <int EPI>
__global__ __launch_bounds__(256, 2) void gemm_bt(const bf16_t* __restrict__ A,
                                                  const bf16_t* __restrict__ Bt,
                                                  void* __restrict__ outp,
                                                  const float* __restrict__ res,
                                                  int M, int N, int K) {
    __shared__ __align__(16) bf16_t ldsA[128 * 64];
    __shared__ __align__(16) bf16_t ldsB[128 * 64];
    int tid = threadIdx.x, lane = tid & 63, w = tid >> 6;
    int lr = lane & 15, lg = lane >> 4;

    // T1: XCD-bijective swizzle, bx-major within each XCD chunk
    int GX = gridDim.x, GYd = gridDim.y;
    int bid = blockIdx.y * GX + blockIdx.x;
    int nwg = GX * GYd;
    int qc = nwg >> 3, rc = nwg & 7;
    int xcd = bid & 7, jj = bid >> 3;
    int wg = (xcd < rc ? xcd * (qc + 1) : rc * (qc + 1) + (xcd - rc) * qc) + jj;
    int bx = wg / GYd;
    int by = wg % GYd;

    int m0 = by * 128, n0 = bx * 128;
    int wr = w >> 1, wc = w & 1;
    f32x4 acc[4][4] = {};
    int srow = w * 8 + (lane >> 3);  // 0..31
    int sslot = lane & 7;

    for (int kt = 0; kt < K; kt += 64) {
        for (int i = 0; i < 4; ++i) {
            int row = i * 32 + srow;
            int sp = sslot ^ (row & 7);
            gload_lds16(A + (size_t)(m0 + row) * K + kt + sp * 8,
                        ldsA + i * 2048 + w * 512);
            gload_lds16(Bt + (size_t)(n0 + row) * K + kt + sp * 8,
                        ldsB + i * 2048 + w * 512);
        }
        asm volatile("s_waitcnt vmcnt(0)" ::: "memory");
        __syncthreads();
        for (int kk = 0; kk < 2; ++kk) {
            bf16x8 af[4], bfm[4];
            for (int x = 0; x < 4; ++x) {
                int ra = wr * 64 + x * 16 + lr;
                int sa = (kk * 4 + lg) ^ (ra & 7);
                af[x] = *(const bf16x8*)(ldsA + ra * 64 + sa * 8);
                int rb = wc * 64 + x * 16 + lr;
                int sb = (kk * 4 + lg) ^ (rb & 7);
                bfm[x] = *(const bf16x8*)(ldsB + rb * 64 + sb * 8);
            }
            for (int mi = 0; mi < 4; ++mi)
                for (int ni = 0; ni < 4; ++ni)
                    acc[mi][ni] = __builtin_amdgcn_mfma_f32_16x16x32_bf16(
                        af[mi], bfm[ni], acc[mi][ni], 0, 0, 0);
        }
        __syncthreads();
    }

    for (int mi = 0; mi < 4; ++mi) {
        int mbase = m0 + wr * 64 + mi * 16 + lg * 4;
        for (int ni = 0; ni < 4; ++ni) {
            int n = n0 + wc * 64 + ni * 16 + lr;
            f32x4 v = acc[mi][ni];
            for (int r = 0; r < 4; ++r) {
                size_t idx = (size_t)(mbase + r) * N + n;
                if (EPI == 0) ((bf16_t*)outp)[idx] = (bf16_t)v[r];
                else          ((float*)outp)[idx] = res[idx] + v[r];
            }
        }
    }
}

// ---------------- Dual-B GEMM: one A-tile, two B-panels, two accumulators ----------------
// reads:MFMA = 24:64 (vs 16:32) -> ~1.33x less LDS traffic per FLOP (LDS-BW-bound fix).
// EPI 0 (QK): out1=bf16(acc1), out2=bf16(acc2).
// EPI 1 (gate/up): out1 = bf16( silu(acc1) * acc2 ).
template <int EPI>
__global__ __launch_bounds__(256, 2) void gemm_dual(const bf16_t* __restrict__ A,
                                                    const bf16_t* __restrict__ B1,
                                                    const bf16_t* __restrict__ B2,
                                                    bf16_t* __restrict__ out1,
                                                    bf16_t* __restrict__ out2,
                                                    int M, int N, int K) {
    __shared__ __align__(16) bf16_t ldsA[128 * 64];
    __shared__ __align__(16) bf16_t ldsB1[128 * 64];
    __shared__ __align__(16) bf16_t ldsB2[128 * 64];
    int tid = threadIdx.x, lane = tid & 63, w = tid >> 6;
    int lr = lane & 15, lg = lane >> 4;

    int GX = gridDim.x, GYd = gridDim.y;
    int bid = blockIdx.y * GX + blockIdx.x;
    int nwg = GX * GYd;
    int qc = nwg >> 3, rc = nwg & 7;
    int xcd = bid & 7, jj = bid >> 3;
    int wg = (xcd < rc ? xcd * (qc + 1) : rc * (qc + 1) + (xcd - rc) * qc) + jj;
    int bx = wg / GYd;
    int by = wg % GYd;

    int m0 = by * 128, n0 = bx * 128;
    int wr = w >> 1, wc = w & 1;
    f32x4 acc1[4][4] = {};
    f32x4 acc2[4][4] = {};
    int srow = w * 8 + (lane >> 3);  // 0..31
    int sslot = lane & 7;

    for (int kt = 0; kt < K; kt += 64) {
        for (int i = 0; i < 4; ++i) {
            int row = i * 32 + srow;
            int sp = sslot ^ (row & 7);
            gload_lds16(A  + (size_t)(m0 + row) * K + kt + sp * 8, ldsA  + i * 2048 + w * 512);
            gload_lds16(B1 + (size_t)(n0 + row) * K + kt + sp * 8, ldsB1 + i * 2048 + w * 512);
            gload_lds16(B2 + (size_t)(n0 + row) * K + kt + sp * 8, ldsB2 + i * 2048 + w * 512);
        }
        asm volatile("s_waitcnt vmcnt(0)" ::: "memory");
        __syncthreads();
        for (int kk = 0; kk < 2; ++kk) {
            bf16x8 af[4], bfm[4];
            for (int x = 0; x < 4; ++x) {
                int ra = wr * 64 + x * 16 + lr;
                af[x] = *(const bf16x8*)(ldsA + ra * 64 + (((kk * 4 + lg) ^ (ra & 7)) * 8));
            }
            for (int x = 0; x < 4; ++x) {
                int rb = wc * 64 + x * 16 + lr;
                bfm[x] = *(const bf16x8*)(ldsB1 + rb * 64 + (((kk * 4 + lg) ^ (rb & 7)) * 8));
            }
            for (int mi = 0; mi < 4; ++mi)
                for (int ni = 0; ni < 4; ++ni)
                    acc1[mi][ni] = __builtin_amdgcn_mfma_f32_16x16x32_bf16(
                        af[mi], bfm[ni], acc1[mi][ni], 0, 0, 0);
            for (int x = 0; x < 4; ++x) {
                int rb = wc * 64 + x * 16 + lr;
                bfm[x] = *(const bf16x8*)(ldsB2 + rb * 64 + (((kk * 4 + lg) ^ (rb & 7)) * 8));
            }
            for (int mi = 0; mi < 4; ++mi)
                for (int ni = 0; ni < 4; ++ni)
                    acc2[mi][ni] = __builtin_amdgcn_mfma_f32_16x16x32_bf16(
                        af[mi], bfm[ni], acc2[mi][ni], 0, 0, 0);
        }
        __syncthreads();
    }

    for (int mi = 0; mi < 4; ++mi) {
        int mbase = m0 + wr * 64 + mi * 16 + lg * 4;
        for (int ni = 0; ni < 4; ++ni) {
            int n = n0 + wc * 64 + ni * 16 + lr;
            f32x4 v1 = acc1[mi][ni];
            f32x4 v2 = acc2[mi][ni];
            for (int r = 0; r < 4; ++r) {
                size_t idx = (size_t)(mbase + r) * N + n;
                if (EPI == 0) {
                    out1[idx] = (bf16_t)v1[r];
                    out2[idx] = (bf16_t)v2[r];
                } else {
                    float g = v1[r];
                    float sg = g / (1.0f + __expf(-g));
                    out1[idx] = (bf16_t)(sg * v2[r]);
                }
            }
        }
    }
}

// ---------------- Flash attention (causal), KVBLK=64, V pre-transposed ----------------
__global__ __launch_bounds__(256, 3) void attn_k(const bf16_t* __restrict__ qb,
                                                 const bf16_t* __restrict__ kb,
                                                 const bf16_t* __restrict__ vtb,
                                                 bf16_t* __restrict__ ab) {
    __shared__ __align__(16) bf16_t ldsK[64 * 128];   // [k][d], 16B slots src-swizzled
    __shared__ __align__(16) bf16_t ldsVt[128 * 64];  // [d][k], 16B slots src-swizzled
    __shared__ __align__(16) float pbuf[4][16][68];   // per wave: [q][k 0..63] 4-col swizzled
    int bid = blockIdx.x;
    int band = 31 - (bid >> 5);      // heavy bands dispatched first
    int bh = bid & 31;
    int b = bh >> 4, h = bh & 15;
    int q0 = band * 64;
    int tid = threadIdx.x, lane = tid & 63, w = tid >> 6;
    int lr = lane & 15, lg = lane >> 4;
    size_t kqbase = ((size_t)b * SS) * DD + h * HDIM;
    size_t vtbase = ((size_t)(b * HH + h)) * HDIM * SS;
    int qw = q0 + w * 16;

    bf16x8 aq[4];
    #pragma unroll
    for (int kd = 0; kd < 4; ++kd)
        aq[kd] = *(const bf16x8*)(qb + kqbase + (size_t)(qw + lr) * DD + kd * 32 + lg * 8);

    f32x4 acc[8] = {};
    float mrun[4], lrun[4];
    #pragma unroll
    for (int r = 0; r < 4; ++r) { mrun[r] = -1e30f; lrun[r] = 0.f; }
    const float scale = 0.08838834764831845f;  // 1/sqrt(128)

    for (int t = 0; t <= band; ++t) {
        int kk0 = t * 64;
        #pragma unroll
        for (int it = 0; it < 4; ++it) {
            int cid = it * 256 + tid;
            int kr = cid >> 4, kslot = cid & 15;
            gload_lds16(kb + kqbase + (size_t)(kk0 + kr) * DD + ((kslot ^ (kr & 7)) * 8),
                        ldsK + it * 2048 + w * 512);
            int vd = cid >> 3, vslot = cid & 7;
            gload_lds16(vtb + vtbase + (size_t)vd * SS + kk0 + ((vslot ^ (vd & 7)) * 8),
                        ldsVt + it * 2048 + w * 512);
        }
        asm volatile("s_waitcnt vmcnt(0)" ::: "memory");
        __syncthreads();

        // QK^T: S[q 16][k 64]
        f32x4 sf[4];
        #pragma unroll
        for (int nf = 0; nf < 4; ++nf) {
            f32x4 d = {};
            int row = nf * 16 + lr;
            #pragma unroll
            for (int kd = 0; kd < 4; ++kd) {
                bf16x8 bk = *(const bf16x8*)(ldsK + row * 128 +
                                             (((kd * 4 + lg) ^ (lr & 7)) * 8));
                d = __builtin_amdgcn_mfma_f32_16x16x32_bf16(aq[kd], bk, d, 0, 0, 0);
            }
            sf[nf] = d;
        }
        float corr[4];
        #pragma unroll
        for (int r = 0; r < 4; ++r) {
            int qg = qw + lg * 4 + r;
            float s[4];
            #pragma unroll
            for (int nf = 0; nf < 4; ++nf) {
                s[nf] = sf[nf][r] * scale;
                if (kk0 + nf * 16 + lr > qg) s[nf] = -1e30f;
            }
            float mx = fmaxf(fmaxf(s[0], s[1]), fmaxf(s[2], s[3]));
            mx = fmaxf(mx, __shfl_xor(mx, 1));
            mx = fmaxf(mx, __shfl_xor(mx, 2));
            mx = fmaxf(mx, __shfl_xor(mx, 4));
            mx = fmaxf(mx, __shfl_xor(mx, 8));
            float mnew = fmaxf(mrun[r], mx);
            float rs = 0.f;
            #pragma unroll
            for (int nf = 0; nf < 4; ++nf) {
                float p = __expf(s[nf] - mnew);
                rs += p;
                pbuf[w][lg * 4 + r][nf * 16 + (lr ^ (r << 2))] = p;
            }
            rs += __shfl_xor(rs, 1); rs += __shfl_xor(rs, 2);
            rs += __shfl_xor(rs, 4); rs += __shfl_xor(rs, 8);
            corr[r] = __expf(mrun[r] - mnew);
            lrun[r] = lrun[r] * corr[r] + rs;
            mrun[r] = mnew;
        }
        #pragma unroll
        for (int df = 0; df < 8; ++df)
            #pragma unroll
            for (int r = 0; r < 4; ++r) acc[df][r] *= corr[r];
        asm volatile("s_waitcnt lgkmcnt(0)" ::: "memory");
        // PV: two K=32 steps; A-frag rebuilt from pbuf (wave-local)
        #pragma unroll
        for (int ks2 = 0; ks2 < 2; ++ks2) {
            int nfA = ks2 * 2 + (lg >> 1);
            int off = (lg & 1) * 8;
            int sw = (lr & 3) << 2;
            float4 a0 = *(const float4*)&pbuf[w][lr][nfA * 16 + (off ^ sw)];
            float4 a1 = *(const float4*)&pbuf[w][lr][nfA * 16 + ((off + 4) ^ sw)];
            bf16x8 ap;
            ap[0] = (bf16_t)a0.x; ap[1] = (bf16_t)a0.y;
            ap[2] = (bf16_t)a0.z; ap[3] = (bf16_t)a0.w;
            ap[4] = (bf16_t)a1.x; ap[5] = (bf16_t)a1.y;
            ap[6] = (bf16_t)a1.z; ap[7] = (bf16_t)a1.w;
            #pragma unroll
            for (int df = 0; df < 8; ++df) {
                bf16x8 bv = *(const bf16x8*)(ldsVt + (df * 16 + lr) * 64 +
                                             (((ks2 * 4 + lg) ^ (lr & 7)) * 8));
                acc[df] = __builtin_amdgcn_mfma_f32_16x16x32_bf16(ap, bv, acc[df], 0, 0, 0);
            }
        }
        __syncthreads();
    }
    #pragma unroll
    for (int df = 0; df < 8; ++df)
        #pragma unroll
        for (int r = 0; r < 4; ++r) {
            int qg = qw + lg * 4 + r;
            ab[kqbase + (size_t)qg * DD + df * 16 + lr] = (bf16_t)(acc[df][r] / lrun[r]);
        }
}

extern "C" void kernel_launch(void* const* d_in, const int* in_sizes, int n_in,
                              void* d_out, int out_size, void* d_ws, size_t ws_size,
                              hipStream_t stream) {
    const float* hs  = (const float*)d_in[0];
    // d_in[1] = attention_mask (exactly causal) — applied analytically
    const float* Wq  = (const float*)d_in[2];
    const float* Wk  = (const float*)d_in[3];
    const float* Wv  = (const float*)d_in[4];
    const float* Wo  = (const float*)d_in[5];
    const float* Wg  = (const float*)d_in[6];
    const float* Wu  = (const float*)d_in[7];
    const float* Wd  = (const float*)d_in[8];
    const float* ln1 = (const float*)d_in[9];
    const float* ln2 = (const float*)d_in[10];

    char* ws = (char*)d_ws;
    const size_t MB = 1u << 20;
    bf16_t* xb     = (bf16_t*)(ws);                 // 16 MiB [M][D]
    bf16_t* qb     = (bf16_t*)(ws + 16 * MB);       // 16 MiB
    bf16_t* kb     = (bf16_t*)(ws + 32 * MB);       // 16 MiB
    bf16_t* vb     = (bf16_t*)(ws + 48 * MB);       // 16 MiB
    bf16_t* vtb    = (bf16_t*)(ws + 64 * MB);       // 16 MiB (dead before hidden is written)
    float*  cosb   = (float*)(ws + 80 * MB);        // 1 MiB (dead before hidden is written)
    float*  sinb   = (float*)(ws + 81 * MB);        // 1 MiB
    float*  hidden = (float*)(ws + 64 * MB);        // 32 MiB f32, written at Wo step
    bf16_t* wtA    = (bf16_t*)(ws + 96 * MB);       // 23.5 MiB transposed-weight scratch A
    bf16_t* wtB    = (bf16_t*)d_out;                // d_out (32 MiB) as scratch B until final gemm
    bf16_t* ab = xb;   // attn out reuses xb
    bf16_t* yb = xb;   // ln2 out reuses xb
    bf16_t* gb = qb;   // h = silu(gate)*up [M][I] = 43 MiB, reuses q/k/v region

    if (ws_size < (size_t)(98 * MB) + (size_t)II * DD * 2) return;

    // 1. LN1
    rmsnorm_k<<<MM, 256, 0, stream>>>(hs, ln1, xb);
    // 2. RoPE tables
    rope_tables_k<<<SS, 128, 0, stream>>>(cosb, sinb);
    // 3-5. Q & K fused (shared A-tile) — dual-B GEMM
    convT_k<<<dim3(DD / 32, DD / 32), 256, 0, stream>>>(Wq, wtA, DD, DD);
    convT_k<<<dim3(DD / 32, DD / 32), 256, 0, stream>>>(Wk, wtB, DD, DD);
    gemm_dual<0><<<dim3(DD / 128, MM / 128), 256, 0, stream>>>(xb, wtA, wtB, qb, kb, MM, DD, DD);
    // 6-7. V projection
    convT_k<<<dim3(DD / 32, DD / 32), 256, 0, stream>>>(Wv, wtA, DD, DD);
    gemm_bt<0><<<dim3(DD / 128, MM / 128), 256, 0, stream>>>(xb, wtA, vb, nullptr, MM, DD, DD);
    // 8. V transpose for attention B-operand staging
    vtrans_k<<<dim3(DD / 32, SS / 32, BB), 256, 0, stream>>>(vb, vtb);
    // 9. RoPE on q,k
    rope_apply_k<<<(MM * HH * 64) / 256, 256, 0, stream>>>(qb, kb, cosb, sinb);
    // 10. attention
    attn_k<<<1024, 256, 0, stream>>>(qb, kb, vtb, ab);
    // 11-12. Wo + residual -> hidden (f32; overwrites vtb/cos/sin, all dead)
    convT_k<<<dim3(DD / 32, DD / 32), 256, 0, stream>>>(Wo, wtA, DD, DD);
    gemm_bt<1><<<dim3(DD / 128, MM / 128), 256, 0, stream>>>(ab, wtA, hidden, hs, MM, DD, DD);
    // 13. LN2
    rmsnorm_k<<<MM, 256, 0, stream>>>(hidden, ln2, yb);
    // 14-16. gate & up fused (shared A-tile) + silu-mul epilogue -> gb
    convT_k<<<dim3(II / 32, DD / 32), 256, 0, stream>>>(Wg, wtA, DD, II);
    convT_k<<<dim3(II / 32, DD / 32), 256, 0, stream>>>(Wu, wtB, DD, II);
    gemm_dual<1><<<dim3(II / 128, MM / 128), 256, 0, stream>>>(yb, wtA, wtB, gb, nullptr, MM, II, DD);
    // 17-18. out = hidden + h @ Wd (f32; overwrites wtB scratch = d_out, now dead)
    convT_k<<<dim3(DD / 32, II / 32), 256, 0, stream>>>(Wd, wtA, II, DD);
    gemm_bt<1><<<dim3(DD / 128, MM / 128), 256, 0, stream>>>(gb, wtA, (float*)d_out, hidden, MM, DD, II);
}